// Round 11
// baseline (165.033 us; speedup 1.0000x reference)
//
#include <hip/hip_runtime.h>
#include <hip/hip_bf16.h>
#include <math.h>

#define BS   32
#define IC   64
#define OC   64
#define HH   128
#define WW   128
#define BANK 256
#define ADDR 64
#define WELEM (OC*IC*9)
#define PLANE (HH*WW)

// xbf padded layout: [b][130 ry][8 g][132 col][8 ic] bf16 (borders zeroed)
#define XROW  (8 * 132 * 8)          // shorts per ry row = 8448
#define XSAMP (130 * XROW)

typedef short short8 __attribute__((ext_vector_type(8)));
typedef float f32x16 __attribute__((ext_vector_type(16)));

__device__ __forceinline__ short f2bf(float f) {
    unsigned u = __builtin_bit_cast(unsigned, f);
    unsigned r = (u + 0x7FFFu + ((u >> 16) & 1u)) >> 16;
    return (short)r;
}

typedef __attribute__((address_space(3))) unsigned int lds_u32;
typedef const __attribute__((address_space(1))) unsigned int g_u32;
__device__ __forceinline__ void gload16(const short* g, short* l) {
    __builtin_amdgcn_global_load_lds((g_u32*)g, (lds_u32*)l, 16, 0, 0);
}

// ---------------- kernel 1: sel_w = softmax(w_addr @ aspace^T) --------------
__global__ __launch_bounds__(BANK) void k_selw(const float* __restrict__ w_addr,
                                               const float* __restrict__ aspace,
                                               float* __restrict__ sel_w) {
    int b = blockIdx.x;
    int n = threadIdx.x;
    const float* wa = w_addr + b * ADDR;
    const float* as = aspace + n * ADDR;
    float dot = 0.f;
#pragma unroll
    for (int k = 0; k < ADDR; ++k) dot = fmaf(wa[k], as[k], dot);

    __shared__ float red[BANK];
    red[n] = dot; __syncthreads();
    for (int s = BANK / 2; s > 0; s >>= 1) {
        if (n < s) red[n] = fmaxf(red[n], red[n + s]);
        __syncthreads();
    }
    float m = red[0]; __syncthreads();
    float e = expf(dot - m);
    red[n] = e; __syncthreads();
    for (int s = BANK / 2; s > 0; s >>= 1) {
        if (n < s) red[n] += red[n + s];
        __syncthreads();
    }
    sel_w[b * BANK + n] = e / red[0];
}

// ---------------- kernel 2: bias[b][o] = softmax(b_addr@aspace^T) @ b_bank --
__global__ __launch_bounds__(BANK) void k_bias(const float* __restrict__ b_addr,
                                               const float* __restrict__ aspace,
                                               const float* __restrict__ b_bank,
                                               float* __restrict__ bias) {
    int bo = blockIdx.x;
    int n  = threadIdx.x;
    const float* ba = b_addr + (size_t)bo * ADDR;
    const float* as = aspace + n * ADDR;
    float dot = 0.f;
#pragma unroll
    for (int k = 0; k < ADDR; ++k) dot = fmaf(ba[k], as[k], dot);

    __shared__ float red[BANK];
    red[n] = dot; __syncthreads();
    for (int s = BANK / 2; s > 0; s >>= 1) {
        if (n < s) red[n] = fmaxf(red[n], red[n + s]);
        __syncthreads();
    }
    float m = red[0]; __syncthreads();
    float e = expf(dot - m);
    red[n] = e; __syncthreads();
    for (int s = BANK / 2; s > 0; s >>= 1) {
        if (n < s) red[n] += red[n + s];
        __syncthreads();
    }
    float denom = red[0]; __syncthreads();
    red[n] = e * b_bank[n]; __syncthreads();
    for (int s = BANK / 2; s > 0; s >>= 1) {
        if (n < s) red[n] += red[n + s];
        __syncthreads();
    }
    if (n == 0) bias[bo] = red[0] / denom;
}

// ---------------- kernel 3: weight mix -> bf16, MFMA-fragment layout --------
// wmb[b][tap(9)][icg(8)][oc(64)][ic8(8)]  (bf16)
// n-batched (8) inner loop: wv[8]+acc[32] fits 64 VGPR -> 8 loads fly
// together, 256 FMAs hide the latency (fixes wv[64] serialization).
__global__ __launch_bounds__(256) void k_wmix(const float* __restrict__ sel_w,
                                              const float* __restrict__ w_bank,
                                              __hip_bfloat16* __restrict__ wmb) {
    __shared__ float s_red[4 * 32 * 64];   // [chunk][b][jl] = 32 KB

    int tid = threadIdx.x;
    int jl  = tid & 63;
    int c   = tid >> 6;
    int jb  = blockIdx.x * 64 + jl;

    int n0 = __builtin_amdgcn_readfirstlane(c * 64);
    const float* selp = sel_w + n0;

    float acc[BS];
#pragma unroll
    for (int b = 0; b < BS; ++b) acc[b] = 0.f;

    for (int nb = 0; nb < 8; ++nb) {
        float wv[8];
#pragma unroll
        for (int i = 0; i < 8; ++i)
            wv[i] = w_bank[(size_t)(n0 + nb * 8 + i) * WELEM + jb];
#pragma unroll
        for (int b = 0; b < BS; ++b)
#pragma unroll
            for (int i = 0; i < 8; ++i)
                acc[b] = fmaf(selp[b * BANK + nb * 8 + i], wv[i], acc[b]);
    }

#pragma unroll
    for (int b = 0; b < BS; ++b)
        s_red[(c * 32 + b) * 64 + jl] = acc[b];
    __syncthreads();

    int B0  = (tid * 8) & 31;
    int jl2 = (tid * 8) >> 5;
    int j   = blockIdx.x * 64 + jl2;
    int o   = j / 576;
    int rem = j - o * 576;
    int i   = rem / 9;
    int tap = rem - i * 9;
    size_t base = ((size_t)tap * 8 + (i >> 3)) * 512 + (size_t)o * 8 + (i & 7);
#pragma unroll
    for (int u = 0; u < 8; ++u) {
        int b = B0 + u;
        float v = s_red[(0 * 32 + b) * 64 + jl2] + s_red[(1 * 32 + b) * 64 + jl2]
                + s_red[(2 * 32 + b) * 64 + jl2] + s_red[(3 * 32 + b) * 64 + jl2];
        short sv = f2bf(v);
        wmb[(size_t)b * (9 * 8 * 64 * 8) + base] = *reinterpret_cast<__hip_bfloat16*>(&sv);
    }
}

// ---------------- kernel 4: x NCHW f32 -> padded group-blocked bf16 ---------
// xbf[b][ry(130)][g(8)][col(132)][8]; ry=gy+1, col=gx+1; borders zeroed.
__global__ __launch_bounds__(256) void k_tr(const float* __restrict__ x,
                                            short* __restrict__ xbf) {
    int bid = blockIdx.x;              // b*130 + ry
    int b  = bid / 130;
    int ry = bid - b * 130;
    short* row = xbf + (size_t)b * XSAMP + (size_t)ry * XROW;
    int tid = threadIdx.x;
    short8 z = {0, 0, 0, 0, 0, 0, 0, 0};

    if (ry == 0 || ry == 129) {        // zero guard rows
        for (int u = tid; u < 1056; u += 256)
            *(short8*)(row + u * 8) = z;
        return;
    }
    int gy = ry - 1;
    const float* xb = x + ((size_t)b * IC * HH + gy) * WW;
    int icg = tid & 7;
    int px0 = (tid >> 3) * 4;

    float4 v[8];
#pragma unroll
    for (int e = 0; e < 8; ++e)
        v[e] = *(const float4*)&xb[(size_t)(icg * 8 + e) * HH * WW + px0];
#pragma unroll
    for (int p = 0; p < 4; ++p) {
        short8 s;
#pragma unroll
        for (int e = 0; e < 8; ++e)
            s[e] = f2bf(((const float*)&v[e])[p]);
        *(short8*)(row + ((size_t)icg * 132 + px0 + p + 1) * 8) = s;
    }
    if (tid < 32) {                    // zero guard cols 0,129 + pad 130,131
        int g = tid >> 2;
        int sel = tid & 3;
        int cz = (sel == 0) ? 0 : (128 + sel);   // 0,129,130,131
        *(short8*)(row + ((size_t)g * 132 + cz) * 8) = z;
    }
}

// ---------------- kernel 5: implicit-GEMM conv, all-async staging -----------
// 2048 blocks = (b, 64 strips of 2 rows), XCD-swizzled; 512 thr / 8 waves.
// wave = (row wr, oc-half oh, px-half ph): 32 oc x 64 px -> 2 acc tiles.
// LDS = x dbuf ONLY (34 KB -> 4 blocks/CU). x staging: each wave copies one
// (ky,g) slice of 132x16B via 3 global_load_lds (zero VGPR, vmcnt drains at
// the post-MFMA barrier). w fragments: 9 coalesced b128 loads/chunk from
// L2-resident wmb straight into registers.
__global__ __launch_bounds__(512, 8) void k_conv(const short* __restrict__ xbf,
                                                 const short* __restrict__ wmb,
                                                 const float* __restrict__ bias,
                                                 float* __restrict__ out) {
    __shared__ short s_x[2][1056 * 8];   // [buf][(ky*2+g)*132+col][ic8] 16.9KB x2
    __shared__ float s_bias[OC];

    int orig    = blockIdx.x;
    int logical = (orig & 7) * 256 + (orig >> 3);   // bijective (2048%8==0)
    int b    = logical >> 6;
    int y0   = (logical & 63) * 2;
    int tid  = threadIdx.x;
    int lane = tid & 63;
    int wv   = tid >> 6;
    int h    = lane >> 5;
    int ln   = lane & 31;
    int wr   = wv & 1;
    int oh   = (wv >> 1) & 1;
    int ph   = wv >> 2;

    if (tid < OC) s_bias[tid] = bias[b * OC + tid];

    const short* xs   = xbf + (size_t)b * XSAMP + (size_t)y0 * XROW;
    const short* wmbs = wmb + (size_t)b * 36864;

    // wave wv stages slice (ky = wv>>1, g = wv&1): 132 16B-units, linear
    int sky = wv >> 1, sgg = wv & 1;
    auto STAGEX = [&](int cc, int bf) {
        const short* gb = xs + (size_t)sky * XROW + (size_t)(2 * cc + sgg) * 1056;
        short* lb = &s_x[bf][(sky * 2 + sgg) * 132 * 8];
        gload16(gb + (size_t)lane * 8, lb);
        gload16(gb + (size_t)(64 + lane) * 8, lb + 64 * 8);
        if (lane < 4) gload16(gb + (size_t)(128 + lane) * 8, lb + 128 * 8);
    };

    f32x16 acc[2];
    acc[0] = (f32x16)0.0f;
    acc[1] = (f32x16)0.0f;

    STAGEX(0, 0);
    __syncthreads();                       // drain -> buf0 ready

    for (int cc = 0; cc < 4; ++cc) {
        int bf = cc & 1;
        if (cc < 3) STAGEX(cc + 1, bf ^ 1);   // async, in flight during MFMA

        short8 areg[9];
#pragma unroll
        for (int tap = 0; tap < 9; ++tap)
            areg[tap] = *(const short8*)(wmbs +
                (size_t)((tap * 8 + 2 * cc + h) * 64 + oh * 32 + ln) * 8);

        const short8* xb8 = (const short8*)s_x[bf];
#pragma unroll
        for (int ky = 0; ky < 3; ++ky) {
#pragma unroll
            for (int kx = 0; kx < 3; ++kx) {
                short8 a = areg[ky * 3 + kx];
#pragma unroll
                for (int nt = 0; nt < 2; ++nt) {
                    short8 bb = xb8[((wr + ky) * 2 + h) * 132 + ph * 64 + nt * 32 + ln + kx];
                    acc[nt] = __builtin_amdgcn_mfma_f32_32x32x16_bf16(a, bb, acc[nt], 0, 0, 0);
                }
            }
        }
        __syncthreads();                   // drain STAGEX(cc+1) + reader fence
    }

    // epilogue: C/D layout col=lane&31, row=(r&3)+8*(r>>2)+4*h
    int y = y0 + wr;
    float* ob = out + (size_t)b * OC * PLANE;
#pragma unroll
    for (int nt = 0; nt < 2; ++nt) {
#pragma unroll
        for (int r = 0; r < 16; ++r) {
            int oc = oh * 32 + (r & 3) + 8 * (r >> 2) + 4 * h;
            int px = ph * 64 + nt * 32 + ln;
            ob[((size_t)oc * HH + y) * WW + px] = acc[nt][r] + s_bias[oc];
        }
    }
}

// ---------------------------------------------------------------------------
extern "C" void kernel_launch(void* const* d_in, const int* in_sizes, int n_in,
                              void* d_out, int out_size, void* d_ws, size_t ws_size,
                              hipStream_t stream) {
    const float* x      = (const float*)d_in[0];
    const float* w_addr = (const float*)d_in[1];
    const float* b_addr = (const float*)d_in[2];
    const float* w_bank = (const float*)d_in[3];
    const float* b_bank = (const float*)d_in[4];
    const float* aspace = (const float*)d_in[5];
    float* out = (float*)d_out;

    char* ws = (char*)d_ws;
    float*          sel_w = (float*)ws;                     // 32768 B
    float*          bias  = (float*)(ws + 32768);           //  8192 B
    __hip_bfloat16* wmb   = (__hip_bfloat16*)(ws + 40960);  // 2359296 B
    short*          xbf   = (short*)(ws + 40960 + 2359296); // 70287360 B

    k_selw<<<BS, BANK, 0, stream>>>(w_addr, aspace, sel_w);
    k_bias<<<BS * OC, BANK, 0, stream>>>(b_addr, aspace, b_bank, bias);
    k_wmix<<<WELEM / 64, 256, 0, stream>>>(sel_w, w_bank, wmb);
    k_tr<<<BS * 130, 256, 0, stream>>>(x, xbf);
    k_conv<<<BS * 64, 512, 0, stream>>>(xbf, (const short*)wmb, bias, out);
}

// Round 12
// 135.489 us; speedup vs baseline: 1.2181x; 1.2181x over previous
//
#include <hip/hip_runtime.h>
#include <hip/hip_bf16.h>
#include <math.h>

#define BS   32
#define IC   64
#define OC   64
#define HH   128
#define WW   128
#define BANK 256
#define ADDR 64
#define WELEM (OC*IC*9)
#define PLANE (HH*WW)

typedef short short8 __attribute__((ext_vector_type(8)));
typedef int   i32x4  __attribute__((ext_vector_type(4)));
typedef float f32x16 __attribute__((ext_vector_type(16)));

__device__ __forceinline__ short f2bf(float f) {
    unsigned u = __builtin_bit_cast(unsigned, f);
    unsigned r = (u + 0x7FFFu + ((u >> 16) & 1u)) >> 16;
    return (short)r;
}

__device__ __forceinline__ int pack_bf2(float lo, float hi) {
    unsigned ul = __builtin_bit_cast(unsigned, lo);
    unsigned uh = __builtin_bit_cast(unsigned, hi);
    unsigned rl = (ul + 0x7FFFu + ((ul >> 16) & 1u)) >> 16;
    unsigned rh = (uh + 0x7FFFu + ((uh >> 16) & 1u)) & 0xFFFF0000u;
    return (int)(rh | (rl & 0xFFFFu));
}

// ---------------- kernel 1: sel_w = softmax(w_addr @ aspace^T) --------------
__global__ __launch_bounds__(BANK) void k_selw(const float* __restrict__ w_addr,
                                               const float* __restrict__ aspace,
                                               float* __restrict__ sel_w) {
    int b = blockIdx.x;
    int n = threadIdx.x;
    const float* wa = w_addr + b * ADDR;
    const float* as = aspace + n * ADDR;
    float dot = 0.f;
#pragma unroll
    for (int k = 0; k < ADDR; ++k) dot = fmaf(wa[k], as[k], dot);

    __shared__ float red[BANK];
    red[n] = dot; __syncthreads();
    for (int s = BANK / 2; s > 0; s >>= 1) {
        if (n < s) red[n] = fmaxf(red[n], red[n + s]);
        __syncthreads();
    }
    float m = red[0]; __syncthreads();
    float e = expf(dot - m);
    red[n] = e; __syncthreads();
    for (int s = BANK / 2; s > 0; s >>= 1) {
        if (n < s) red[n] += red[n + s];
        __syncthreads();
    }
    sel_w[b * BANK + n] = e / red[0];
}

// ---------------- kernel 2: bias[b][o] = softmax(b_addr@aspace^T) @ b_bank --
__global__ __launch_bounds__(BANK) void k_bias(const float* __restrict__ b_addr,
                                               const float* __restrict__ aspace,
                                               const float* __restrict__ b_bank,
                                               float* __restrict__ bias) {
    int bo = blockIdx.x;
    int n  = threadIdx.x;
    const float* ba = b_addr + (size_t)bo * ADDR;
    const float* as = aspace + n * ADDR;
    float dot = 0.f;
#pragma unroll
    for (int k = 0; k < ADDR; ++k) dot = fmaf(ba[k], as[k], dot);

    __shared__ float red[BANK];
    red[n] = dot; __syncthreads();
    for (int s = BANK / 2; s > 0; s >>= 1) {
        if (n < s) red[n] = fmaxf(red[n], red[n + s]);
        __syncthreads();
    }
    float m = red[0]; __syncthreads();
    float e = expf(dot - m);
    red[n] = e; __syncthreads();
    for (int s = BANK / 2; s > 0; s >>= 1) {
        if (n < s) red[n] += red[n + s];
        __syncthreads();
    }
    float denom = red[0]; __syncthreads();
    red[n] = e * b_bank[n]; __syncthreads();
    for (int s = BANK / 2; s > 0; s >>= 1) {
        if (n < s) red[n] += red[n + s];
        __syncthreads();
    }
    if (n == 0) bias[bo] = red[0] / denom;
}

// ---------------- kernel 3: weight mix -> bf16 (R5-proven split-K) ----------
// wmb[b][tap(9)][icg(8)][oc(64)][ic8(8)]  (bf16)
__global__ __launch_bounds__(256) void k_wmix(const float* __restrict__ sel_w,
                                              const float* __restrict__ w_bank,
                                              __hip_bfloat16* __restrict__ wmb) {
    __shared__ float s_red[4 * 32 * 64];   // [chunk][b][jl] = 32 KB

    int tid = threadIdx.x;
    int jl  = tid & 63;
    int c   = tid >> 6;
    int jb  = blockIdx.x * 64 + jl;

    int n0 = __builtin_amdgcn_readfirstlane(c * 64);
    const float* selp = sel_w + n0;

    float wv[64];
#pragma unroll
    for (int n = 0; n < 64; ++n)
        wv[n] = w_bank[(size_t)(n0 + n) * WELEM + jb];

    float acc[BS];
#pragma unroll
    for (int b = 0; b < BS; ++b) acc[b] = 0.f;
#pragma unroll
    for (int b = 0; b < BS; ++b)
#pragma unroll
        for (int n = 0; n < 64; ++n)
            acc[b] = fmaf(selp[b * BANK + n], wv[n], acc[b]);

#pragma unroll
    for (int b = 0; b < BS; ++b)
        s_red[(c * 32 + b) * 64 + jl] = acc[b];
    __syncthreads();

    int B0  = (tid * 8) & 31;
    int jl2 = (tid * 8) >> 5;
    int j   = blockIdx.x * 64 + jl2;
    int o   = j / 576;
    int rem = j - o * 576;
    int i   = rem / 9;
    int tap = rem - i * 9;
    size_t base = ((size_t)tap * 8 + (i >> 3)) * 512 + (size_t)o * 8 + (i & 7);
#pragma unroll
    for (int u = 0; u < 8; ++u) {
        int b = B0 + u;
        float v = s_red[(0 * 32 + b) * 64 + jl2] + s_red[(1 * 32 + b) * 64 + jl2]
                + s_red[(2 * 32 + b) * 64 + jl2] + s_red[(3 * 32 + b) * 64 + jl2];
        short sv = f2bf(v);
        wmb[(size_t)b * (9 * 8 * 64 * 8) + base] = *reinterpret_cast<__hip_bfloat16*>(&sv);
    }
}

// ---------------- kernel 4: FUSED implicit-GEMM conv (reads fp32 NCHW) ------
// 2048 blocks = (b, 64 strips of 2 rows), XCD-swizzled; 512 thr / 8 waves.
// wave = (row wr, oc-half oh, px-half ph): 32 oc x 64 px -> 2 acc tiles.
// LDS x-layout: [ky4][g2][icpair p4][136 dwords]; dword = bf16(ic=2p | ic=2p+1).
// Staging/thread/chunk: 4x float4 px-contiguous loads + 8 pack + 2 b128 writes
// (lane-contiguous, aligned, conflict-free). Fragment = 4x ds_read_b32
// (stride 544B, lanes stride-1 -> free). areg loads issued BEFORE x-prefetch
// so MFMA's vmcnt wait doesn't drain the x loads.
__global__ __launch_bounds__(512, 4) void k_conv(const float* __restrict__ x,
                                                 const short* __restrict__ wmb,
                                                 const float* __restrict__ bias,
                                                 float* __restrict__ out) {
    __shared__ int  s_x[2][4 * 2 * 4 * 136];   // 4352 dwords = 17408 B per buf
    __shared__ float s_bias[OC];

    int orig    = blockIdx.x;
    int logical = (orig & 7) * 256 + (orig >> 3);   // bijective (2048%8==0)
    int b    = logical >> 6;
    int y0   = (logical & 63) * 2;
    int tid  = threadIdx.x;
    int lane = tid & 63;
    int wv   = tid >> 6;
    int h    = lane >> 5;
    int ln   = lane & 31;
    int wr   = wv & 1;
    int oh   = (wv >> 1) & 1;
    int ph   = wv >> 2;

    if (tid < OC) s_bias[tid] = bias[b * OC + tid];
    // zero halo slots (c=0 -> slot 3, c=129 -> slot 132) for all 32 rows x 2 bufs
    if (tid < 128) {
        int buf  = tid >> 6;
        int row  = (tid & 63) >> 1;
        int slot = (tid & 1) ? 132 : 3;
        s_x[buf][row * 136 + slot] = 0;
    }

    const float* xb   = x + (size_t)b * IC * PLANE;
    const short* wmbs = wmb + (size_t)b * 36864;

    // ---- staging descriptors: unit u = k*512+tid, u<1024 ----
    // u -> ky=u>>8, g=(u>>7)&1, p=(u>>5)&3, q=u&31
    int x_goff[2], x_lds[2], x_icb[2]; bool x_ok[2];
#pragma unroll
    for (int k = 0; k < 2; ++k) {
        int u  = k * 512 + tid;
        int ky = u >> 8;
        int g  = (u >> 7) & 1;
        int p  = (u >> 5) & 3;
        int q  = u & 31;
        int gy = y0 - 1 + ky;
        x_ok[k]   = ((unsigned)gy < (unsigned)HH);
        x_icb[k]  = g * 8 + 2 * p;
        x_goff[k] = gy * WW + 4 * q;
        x_lds[k]  = ((ky * 2 + g) * 4 + p) * 136 + 4 + 4 * q;
    }

    float4 xlo[2], xhi[2];

    auto LOADX = [&](int cc) {
#pragma unroll
        for (int k = 0; k < 2; ++k) {
            if (x_ok[k]) {
                const float* p = xb + (size_t)(cc * 16 + x_icb[k]) * PLANE + x_goff[k];
                xlo[k] = *(const float4*)p;
                xhi[k] = *(const float4*)(p + PLANE);
            } else {
                xlo[k] = make_float4(0.f, 0.f, 0.f, 0.f);
                xhi[k] = make_float4(0.f, 0.f, 0.f, 0.f);
            }
        }
    };
    auto STOREX = [&](int bf) {
#pragma unroll
        for (int k = 0; k < 2; ++k) {
            i32x4 d;
#pragma unroll
            for (int j = 0; j < 4; ++j)
                d[j] = pack_bf2(((const float*)&xlo[k])[j], ((const float*)&xhi[k])[j]);
            *(i32x4*)&s_x[bf][x_lds[k]] = d;      // b128, aligned, lane-contiguous
        }
    };

    f32x16 acc[2];
    acc[0] = (f32x16)0.0f;
    acc[1] = (f32x16)0.0f;

    LOADX(0);
    STOREX(0);
    __syncthreads();

    for (int cc = 0; cc < 4; ++cc) {
        int bf = cc & 1;

        // areg loads FIRST (MFMA waits on these; x-prefetch stays outstanding)
        short8 areg[9];
#pragma unroll
        for (int tap = 0; tap < 9; ++tap)
            areg[tap] = *(const short8*)(wmbs +
                (size_t)((tap * 8 + 2 * cc + h) * 64 + oh * 32 + ln) * 8);

        if (cc < 3) LOADX(cc + 1);        // 4 float4 in flight during MFMA

        const int* xi = (const int*)s_x[bf];
#pragma unroll
        for (int ky = 0; ky < 3; ++ky) {
#pragma unroll
            for (int kx = 0; kx < 3; ++kx) {
                short8 a = areg[ky * 3 + kx];
#pragma unroll
                for (int nt = 0; nt < 2; ++nt) {
                    int px   = ph * 64 + nt * 32 + ln;
                    int base = (((wr + ky) * 2 + h) * 4) * 136 + px + kx + 3;
                    i32x4 d;
                    d[0] = xi[base];
                    d[1] = xi[base + 136];
                    d[2] = xi[base + 272];
                    d[3] = xi[base + 408];
                    short8 bb = __builtin_bit_cast(short8, d);
                    acc[nt] = __builtin_amdgcn_mfma_f32_32x32x16_bf16(a, bb, acc[nt], 0, 0, 0);
                }
            }
        }
        if (cc < 3) STOREX(bf ^ 1);       // vmcnt(0) drain lands after MFMA
        __syncthreads();
    }

    // epilogue: C/D layout col=lane&31, row=(r&3)+8*(r>>2)+4*h
    int y = y0 + wr;
    float* ob = out + (size_t)b * OC * PLANE;
#pragma unroll
    for (int nt = 0; nt < 2; ++nt) {
#pragma unroll
        for (int r = 0; r < 16; ++r) {
            int oc = oh * 32 + (r & 3) + 8 * (r >> 2) + 4 * h;
            int px = ph * 64 + nt * 32 + ln;
            ob[((size_t)oc * HH + y) * WW + px] = acc[nt][r] + s_bias[oc];
        }
    }
}

// ---------------------------------------------------------------------------
extern "C" void kernel_launch(void* const* d_in, const int* in_sizes, int n_in,
                              void* d_out, int out_size, void* d_ws, size_t ws_size,
                              hipStream_t stream) {
    const float* x      = (const float*)d_in[0];
    const float* w_addr = (const float*)d_in[1];
    const float* b_addr = (const float*)d_in[2];
    const float* w_bank = (const float*)d_in[3];
    const float* b_bank = (const float*)d_in[4];
    const float* aspace = (const float*)d_in[5];
    float* out = (float*)d_out;

    char* ws = (char*)d_ws;
    float*          sel_w = (float*)ws;                     // 32768 B
    float*          bias  = (float*)(ws + 32768);           //  8192 B
    __hip_bfloat16* wmb   = (__hip_bfloat16*)(ws + 40960);  // 2359296 B

    k_selw<<<BS, BANK, 0, stream>>>(w_addr, aspace, sel_w);
    k_bias<<<BS * OC, BANK, 0, stream>>>(b_addr, aspace, b_bank, bias);
    k_wmix<<<WELEM / 64, 256, 0, stream>>>(sel_w, w_bank, wmb);
    k_conv<<<BS * 64, 512, 0, stream>>>(x, (const short*)wmb, bias, out);
}